// Round 11
// baseline (616.607 us; speedup 1.0000x reference)
//
#include <hip/hip_runtime.h>

// MixHopConv, 8 GCN props on [N,2] fp32.
// R10 lesson: k_sortA (top dispatch, 86us) was barrier+latency bound, not
// memory bound (FETCH 55MB, VALUBusy 17%, occupancy 36%): ~40 __syncthreads
// from 3 naive 512-thread LDS scans + a serial 15.6-iteration dependent-load
// run copy + 57KB LDS capping at 2 blocks/CU.
// R11 (sortA only): wave-shuffle scans (6 barriers total), per-thread
// binary-search copy with 21 independent loads (odd stride -> conflict-free
// LDS writes), LDS diet to 53.2KB -> 3 blocks/CU.
// col entry: (local_dst<<19)|src (src < 2^19; local_dst 0..511; 512=sentinel).

constexpr int NN = 500000;
constexpr int NE = 8000000;
constexpr int STEP_DIM = 8;
constexpr int HIDM1 = 7;

constexpr int BSH  = 9;
constexpr int BNOD = 1 << BSH;                  // 512 nodes / bucket
constexpr int NBUK = (NN + BNOD - 1) / BNOD;    // 977
constexpr int NQ   = 4;                         // src quarters (src>>17)
constexpr int SUBQ = 2560;                      // padded sub-slot (mean ~2048, +11 sigma)
constexpr int SLOT = NQ * SUBQ;                 // 10240
constexpr int KEYS = NQ * BNOD;                 // 2048 sort bins
constexpr unsigned SENT = (unsigned)BNOD << 19; // sentinel -> dump row

constexpr int PA_NBLK = 500;
constexpr int PA_EPB  = NE / PA_NBLK;           // 16000 edges / chunk
constexpr int PA_QPB  = PA_EPB / 4;
constexpr int PA_SC   = NBUK + 1;               // starts2 stride (978)

typedef unsigned u32x4 __attribute__((ext_vector_type(4)));

// logical position within a sub-slot -> physical (wave-coalesced: 4 int4-laid
// edges + 1 single per thread; wave span 320)
__device__ __forceinline__ int swizQ(int p) {
  int w = p / 320;
  int r = p - w * 320;
  int l = r / 5;
  int o = r - l * 5;
  return w * 320 + (o < 4 ? l * 4 + o : 256 + l);
}

__device__ __forceinline__ int wave_iscan(int v, int lane) {
#pragma unroll
  for (int off = 1; off < 64; off <<= 1) {
    int n = __shfl_up(v, off, 64);
    if (lane >= off) v += n;
  }
  return v;
}

// ---- phase 1: per-chunk LDS counting sort by bucket, linear stream-out -----

__global__ __launch_bounds__(512) void k_lsort(const int* __restrict__ src,
                                               const int* __restrict__ dst,
                                               unsigned* __restrict__ colraw,
                                               int* __restrict__ starts2) {
  __shared__ unsigned stage[PA_EPB];   // 62.5 KB
  __shared__ int hist[NBUK];
  __shared__ int tsum[512];
  int b = blockIdx.x, t = threadIdx.x;
  for (int h = t; h < NBUK; h += 512) hist[h] = 0;
  __syncthreads();
  const int4* d4p = (const int4*)dst + (size_t)b * PA_QPB;
  const int4* s4p = (const int4*)src + (size_t)b * PA_QPB;
  for (int i = t; i < PA_QPB; i += 512) {
    int4 d = d4p[i];
    atomicAdd(&hist[d.x >> BSH], 1);
    atomicAdd(&hist[d.y >> BSH], 1);
    atomicAdd(&hist[d.z >> BSH], 1);
    atomicAdd(&hist[d.w >> BSH], 1);
  }
  __syncthreads();
  int h0 = 2 * t, h1 = 2 * t + 1;
  int a0 = (h0 < NBUK) ? hist[h0] : 0;
  int a1 = (h1 < NBUK) ? hist[h1] : 0;
  tsum[t] = a0 + a1;
  __syncthreads();
  for (int o = 1; o < 512; o <<= 1) {
    int v = (t >= o) ? tsum[t - o] : 0;
    __syncthreads();
    tsum[t] += v;
    __syncthreads();
  }
  int ex = tsum[t] - (a0 + a1);
  __syncthreads();
  if (h0 < NBUK) hist[h0] = ex;
  if (h1 < NBUK) hist[h1] = ex + a0;
  __syncthreads();
  int* st = starts2 + (size_t)b * PA_SC;
  for (int h = t; h < NBUK; h += 512) st[h] = hist[h];
  if (t == 0) st[NBUK] = PA_EPB;
  __syncthreads();
  for (int i = t; i < PA_QPB; i += 512) {
    int4 d = d4p[i];
    int4 s = s4p[i];
    int p0 = atomicAdd(&hist[d.x >> BSH], 1);
    stage[p0] = ((unsigned)(d.x & (BNOD - 1)) << 19) | (unsigned)s.x;
    int p1 = atomicAdd(&hist[d.y >> BSH], 1);
    stage[p1] = ((unsigned)(d.y & (BNOD - 1)) << 19) | (unsigned)s.y;
    int p2 = atomicAdd(&hist[d.z >> BSH], 1);
    stage[p2] = ((unsigned)(d.z & (BNOD - 1)) << 19) | (unsigned)s.z;
    int p3 = atomicAdd(&hist[d.w >> BSH], 1);
    stage[p3] = ((unsigned)(d.w & (BNOD - 1)) << 19) | (unsigned)s.w;
  }
  __syncthreads();
  u32x4* out4 = (u32x4*)(colraw + (size_t)b * PA_EPB);
  for (int i = t; i < PA_QPB; i += 512) {
    u32x4 q;
    q[0] = stage[4 * i + 0];
    q[1] = stage[4 * i + 1];
    q[2] = stage[4 * i + 2];
    q[3] = stage[4 * i + 3];
    __builtin_nontemporal_store(q, out4 + i);
  }
}

// ---- phase 2: binary-search copy + (quarter,dst) sort + swizzle ------------
// Also emits dis[i] and the folded layer-0 gather table qtab.

__global__ __launch_bounds__(512) void k_sortA(const unsigned* __restrict__ colraw,
                                               const int* __restrict__ starts2,
                                               unsigned* __restrict__ col2,
                                               const float2* __restrict__ X,
                                               const float* __restrict__ W0,
                                               const float* __restrict__ step_emb,
                                               const int* __restrict__ step_index,
                                               float* __restrict__ dis,
                                               float2* __restrict__ qtab) {
  __shared__ unsigned stage[SLOT];     // 40 KB
  __shared__ int hist[KEYS];           // 8 KB
  __shared__ int rp[PA_NBLK + 1];      // run start positions (2 KB)
  __shared__ int rs[PA_NBLK];          // run source offsets (2 KB)
  __shared__ int wpart[8];
  __shared__ int qsh[5];
  int h = blockIdx.x, t = threadIdx.x;
  int wv = t >> 6, lane = t & 63;
  // run lengths from starts2 (one run per chunk)
  int s = 0, len = 0;
  if (t < PA_NBLK) {
    s = starts2[(size_t)t * PA_SC + h];
    len = starts2[(size_t)t * PA_SC + h + 1] - s;
  }
  // zero hist bins (owned 4/thread) before first barrier
  hist[4 * t] = 0;
  hist[4 * t + 1] = 0;
  hist[4 * t + 2] = 0;
  hist[4 * t + 3] = 0;
  // wave scan of lengths
  int incl = wave_iscan(len, lane);
  if (lane == 63) wpart[wv] = incl;
  __syncthreads();
  int wpre = 0, tot = 0;
#pragma unroll
  for (int k = 0; k < 8; ++k) {
    int pv = wpart[k];
    if (k < wv) wpre += pv;
    tot += pv;
  }
  int pos = wpre + incl - len;  // exclusive prefix
  if (t < PA_NBLK) {
    rp[t] = pos;
    rs[t] = s;
  }
  if (t == 511) rp[PA_NBLK] = tot;
  __syncthreads();
  int ns = tot;
  if (ns > SLOT) ns = SLOT;  // statistically never
  // per-thread copy of 21 contiguous stage positions (odd stride: no LDS bank
  // conflict); run located by 9-step binary search, 21 independent loads
  {
    int p = t * 21;
    if (p < ns) {
      int r = 0;
#pragma unroll
      for (int step = 256; step >= 1; step >>= 1) {
        int nr = r + step;
        if (nr <= PA_NBLK && rp[nr] <= p) r = nr;
      }
      int rstart = rp[r], rend = rp[r + 1], sbase = rs[r];
#pragma unroll
      for (int k = 0; k < 21; ++k) {
        int pp = p + k;
        if (pp >= ns) break;
        while (pp >= rend) {
          ++r;
          rstart = rend;
          rend = rp[r + 1];
          sbase = rs[r];
        }
        stage[pp] = colraw[(size_t)r * PA_EPB + sbase + (pp - rstart)];
      }
    }
  }
  __syncthreads();
  // histogram over (quarter, local_dst)
  for (int i = t; i < ns; i += 512)
    atomicAdd(&hist[(int)(((stage[i] >> 17) & 3u) * BNOD) + (int)(stage[i] >> 19)], 1);
  __syncthreads();
  int deg = hist[t] + hist[t + 512] + hist[t + 1024] + hist[t + 1536];
  int a0 = hist[4 * t], a1 = hist[4 * t + 1], a2 = hist[4 * t + 2], a3 = hist[4 * t + 3];
  int ssum = a0 + a1 + a2 + a3;
  int incl2 = wave_iscan(ssum, lane);
  if (lane == 63) wpart[wv] = incl2;
  __syncthreads();
  int wpre2 = 0;
#pragma unroll
  for (int k = 0; k < 8; ++k) {
    if (k < wv) wpre2 += wpart[k];
  }
  int ex = wpre2 + incl2 - ssum;
  hist[4 * t] = ex;
  hist[4 * t + 1] = ex + a0;
  hist[4 * t + 2] = ex + a0 + a1;
  hist[4 * t + 3] = ex + a0 + a1 + a2;
  if ((t & 127) == 0) qsh[t >> 7] = ex;
  if (t == 511) qsh[4] = ns;
  __syncthreads();
  unsigned* base = col2 + (size_t)h * SLOT;
  for (int i = t; i < ns; i += 512) {
    unsigned p = stage[i];
    int k = (int)(((p >> 17) & 3u) * BNOD) + (int)(p >> 19);
    int posQ = atomicAdd(&hist[k], 1) - qsh[k >> 9];
    if (posQ < SUBQ) base[(k >> 9) * SUBQ + swizQ(posQ)] = p;
  }
  for (int q = 0; q < NQ; ++q) {
    int cnt = qsh[q + 1] - qsh[q];
    if (cnt > SUBQ) cnt = SUBQ;
    if (cnt < 0) cnt = 0;
    for (int j = cnt + t; j < SUBQ; j += 512) base[q * SUBQ + swizQ(j)] = SENT;
  }
  // node init: dis + folded layer-0 gather table
  int i = (h << BSH) + t;
  if (i < NN) {
    float d = rsqrtf((float)deg + 1.0f);
    dis[i] = d;
    float2 x = X[i];
    const float* sv = step_emb + step_index[0] * STEP_DIM;
    float c1_0 = 0.f, c1_1 = 0.f;
#pragma unroll
    for (int j = 0; j < STEP_DIM; ++j) {
      c1_0 += sv[j] * W0[20 + (2 + j) * 2 + 0];
      c1_1 += sv[j] * W0[20 + (2 + j) * 2 + 1];
    }
    qtab[i] = make_float2(d * (x.x * W0[20] + x.y * W0[22] + c1_0),
                          d * (x.x * W0[21] + x.y * W0[23] + c1_1));
  }
}

// ---- layers: batched col2 preload + depth-5 gather prefetch ----------------

__global__ __launch_bounds__(512, 8) void k_blayer0(const unsigned int* __restrict__ col2,
                                                    const float2* __restrict__ qtab,
                                                    const float2* __restrict__ X,
                                                    const float* __restrict__ dis,
                                                    const float* __restrict__ W0,
                                                    const float* __restrict__ b0,
                                                    const float* __restrict__ step_emb,
                                                    const int* __restrict__ step_index,
                                                    float2* __restrict__ xs_out) {
  __shared__ float acc[(BNOD + 1) * 2];
  int b = blockIdx.x, t = threadIdx.x;
  for (int j = t; j < (BNOD + 1) * 2; j += 512) acc[j] = 0.f;
  __syncthreads();
  int w = t >> 6, l = t & 63;
  const unsigned* bp = col2 + (size_t)b * SLOT + w * 320;
  unsigned ebuf[NQ * 5];
#pragma unroll
  for (int q = 0; q < NQ; ++q) {
    u32x4 v = __builtin_nontemporal_load((const u32x4*)(bp + q * SUBQ + l * 4));
    ebuf[q * 5 + 0] = v[0];
    ebuf[q * 5 + 1] = v[1];
    ebuf[q * 5 + 2] = v[2];
    ebuf[q * 5 + 3] = v[3];
    ebuf[q * 5 + 4] = __builtin_nontemporal_load(bp + q * SUBQ + 256 + l);
  }
  int cur = BNOD;
  float rx = 0.f, ry = 0.f;
#pragma unroll
  for (int q = 0; q < NQ; ++q) {
    float2 vals[5];
#pragma unroll
    for (int j = 0; j < 5; ++j) vals[j] = qtab[ebuf[q * 5 + j] & 0x7FFFF];
#pragma unroll
    for (int j = 0; j < 5; ++j) {
      unsigned p = ebuf[q * 5 + j];
      int ld = (int)(p >> 19);
      if (ld != cur) {
        atomicAdd(&acc[cur * 2 + 0], rx);
        atomicAdd(&acc[cur * 2 + 1], ry);
        cur = ld;
        rx = vals[j].x; ry = vals[j].y;
      } else {
        rx += vals[j].x; ry += vals[j].y;
      }
    }
  }
  atomicAdd(&acc[cur * 2 + 0], rx);
  atomicAdd(&acc[cur * 2 + 1], ry);
  __syncthreads();
  const float* sv = step_emb + step_index[0] * STEP_DIM;
  float c00 = b0[0] + b0[2], c01 = b0[1] + b0[3];
#pragma unroll
  for (int j = 0; j < STEP_DIM; ++j) {
    c00 += sv[j] * W0[(2 + j) * 2 + 0];
    c01 += sv[j] * W0[(2 + j) * 2 + 1];
  }
  int i = (b << BSH) + t;
  if (i < NN) {
    float d = dis[i];
    float2 x = X[i];
    float2 qv = qtab[i];
    float h0 = c00 + x.x * W0[0] + x.y * W0[2] + d * (acc[t * 2 + 0] + qv.x);
    float h1 = c01 + x.x * W0[1] + x.y * W0[3] + d * (acc[t * 2 + 1] + qv.y);
    h0 = fmaxf(h0, 0.f);
    h1 = fmaxf(h1, 0.f);
    xs_out[i] = make_float2(d * h0, d * h1);
  }
}

__global__ __launch_bounds__(512, 8) void k_blayer(const unsigned int* __restrict__ col2,
                                                   const float* __restrict__ dis,
                                                   const float2* __restrict__ xs_in,
                                                   const float* __restrict__ W,
                                                   const float* __restrict__ bb,
                                                   float2* __restrict__ xs_out,
                                                   float2* __restrict__ out,
                                                   int last) {
  __shared__ float acc[(BNOD + 1) * 2];
  int b = blockIdx.x, t = threadIdx.x;
  for (int j = t; j < (BNOD + 1) * 2; j += 512) acc[j] = 0.f;
  __syncthreads();
  int w = t >> 6, l = t & 63;
  const unsigned* bp = col2 + (size_t)b * SLOT + w * 320;
  unsigned ebuf[NQ * 5];
#pragma unroll
  for (int q = 0; q < NQ; ++q) {
    u32x4 v = __builtin_nontemporal_load((const u32x4*)(bp + q * SUBQ + l * 4));
    ebuf[q * 5 + 0] = v[0];
    ebuf[q * 5 + 1] = v[1];
    ebuf[q * 5 + 2] = v[2];
    ebuf[q * 5 + 3] = v[3];
    ebuf[q * 5 + 4] = __builtin_nontemporal_load(bp + q * SUBQ + 256 + l);
  }
  int cur = BNOD;
  float rx = 0.f, ry = 0.f;
#pragma unroll
  for (int q = 0; q < NQ; ++q) {
    float2 vals[5];
#pragma unroll
    for (int j = 0; j < 5; ++j) vals[j] = xs_in[ebuf[q * 5 + j] & 0x7FFFF];
#pragma unroll
    for (int j = 0; j < 5; ++j) {
      unsigned p = ebuf[q * 5 + j];
      int ld = (int)(p >> 19);
      if (ld != cur) {
        atomicAdd(&acc[cur * 2 + 0], rx);
        atomicAdd(&acc[cur * 2 + 1], ry);
        cur = ld;
        rx = vals[j].x; ry = vals[j].y;
      } else {
        rx += vals[j].x; ry += vals[j].y;
      }
    }
  }
  atomicAdd(&acc[cur * 2 + 0], rx);
  atomicAdd(&acc[cur * 2 + 1], ry);
  __syncthreads();
  int i = (b << BSH) + t;
  if (i < NN) {
    float d = dis[i];
    float2 xsv = xs_in[i];
    float inv = 1.0f / d;
    float xx = xsv.x * inv, xy = xsv.y * inv;
    float px = d * (acc[t * 2 + 0] + xsv.x);
    float py = d * (acc[t * 2 + 1] + xsv.y);
    float h0 = bb[0] + bb[2] + xx * W[0] + xy * W[2] + px * W[4] + py * W[6];
    float h1 = bb[1] + bb[3] + xx * W[1] + xy * W[3] + px * W[5] + py * W[7];
    h0 = fmaxf(h0, 0.f);
    h1 = fmaxf(h1, 0.f);
    if (last) {
      out[i] = make_float2(h0, h1);
    } else {
      xs_out[i] = make_float2(d * h0, d * h1);
    }
  }
}

// ---- driver ----------------------------------------------------------------

extern "C" void kernel_launch(void* const* d_in, const int* in_sizes, int n_in,
                              void* d_out, int out_size, void* d_ws, size_t ws_size,
                              hipStream_t stream) {
  const float2* X        = (const float2*)d_in[0];
  const int*    edge     = (const int*)d_in[1];
  const int*    src      = edge;
  const int*    dstp     = edge + NE;
  const int*    step_idx = (const int*)d_in[2];
  const float*  step_emb = (const float*)d_in[3];
  const float*  W0       = (const float*)d_in[4];
  const float*  b0       = (const float*)d_in[5];
  const float*  Wh       = (const float*)d_in[6];
  const float*  bbias    = (const float*)d_in[7];

  // ws ints: [col2: 977*10240][colraw: NE][starts2: 500*978 pad]
  //          [dis: 500224][bufA: 1000448][bufB: 1000448]  = 20,994,608 ints (~84 MB)
  int*      ip      = (int*)d_ws;
  unsigned* col2    = (unsigned*)ip;
  size_t    o       = (size_t)NBUK * SLOT;
  unsigned* colraw  = (unsigned*)(ip + o);  o += NE;
  int*      starts2 = ip + o;               o += ((size_t)PA_NBLK * PA_SC + 8) & ~(size_t)3;
  float*    dis     = (float*)(ip + o);     o += 500224;
  float2*   bufA    = (float2*)(ip + o);    o += 2 * 500224;
  float2*   bufB    = (float2*)(ip + o);

  k_lsort<<<PA_NBLK, 512, 0, stream>>>(src, dstp, colraw, starts2);
  k_sortA<<<NBUK, 512, 0, stream>>>(colraw, starts2, col2, X, W0,
                                    step_emb, step_idx, dis, bufA);

  k_blayer0<<<NBUK, 512, 0, stream>>>(col2, bufA, X, dis, W0, b0,
                                      step_emb, step_idx, bufB);
  float2* cur = bufB;
  float2* nxt = bufA;
  for (int l = 0; l < HIDM1; ++l) {
    k_blayer<<<NBUK, 512, 0, stream>>>(col2, dis, cur, Wh + l * 8,
                                       bbias + l * 4, nxt, (float2*)d_out,
                                       l == HIDM1 - 1 ? 1 : 0);
    float2* tmp = cur;
    cur = nxt;
    nxt = tmp;
  }
}

// Round 12
// 551.590 us; speedup vs baseline: 1.1179x; 1.1179x over previous
//
#include <hip/hip_runtime.h>

// MixHopConv, 8 GCN props on [N,2] fp32.
// R11 lesson: per-thread binary-search copy re-created the R7 L1-thrash (64
// scattered windows per wave -> 285 MB FETCH). R12: recombine the verified
// halves — R10's cooperative 16-lane run copy (line-local reads, 55 MB) +
// R11's wave-shuffle scans (~6 barriers vs ~40). LDS diet (drop rl; length
// derived from rp) -> 53.2 KB -> 3 blocks/CU.
// col entry: (local_dst<<19)|src (src < 2^19; local_dst 0..511; 512=sentinel).

constexpr int NN = 500000;
constexpr int NE = 8000000;
constexpr int STEP_DIM = 8;
constexpr int HIDM1 = 7;

constexpr int BSH  = 9;
constexpr int BNOD = 1 << BSH;                  // 512 nodes / bucket
constexpr int NBUK = (NN + BNOD - 1) / BNOD;    // 977
constexpr int NQ   = 4;                         // src quarters (src>>17)
constexpr int SUBQ = 2560;                      // padded sub-slot (mean ~2048, +11 sigma)
constexpr int SLOT = NQ * SUBQ;                 // 10240
constexpr int KEYS = NQ * BNOD;                 // 2048 sort bins
constexpr unsigned SENT = (unsigned)BNOD << 19; // sentinel -> dump row

constexpr int PA_NBLK = 500;
constexpr int PA_EPB  = NE / PA_NBLK;           // 16000 edges / chunk
constexpr int PA_QPB  = PA_EPB / 4;
constexpr int PA_SC   = NBUK + 1;               // starts2 stride (978)

typedef unsigned u32x4 __attribute__((ext_vector_type(4)));

// logical position within a sub-slot -> physical (wave-coalesced: 4 int4-laid
// edges + 1 single per thread; wave span 320)
__device__ __forceinline__ int swizQ(int p) {
  int w = p / 320;
  int r = p - w * 320;
  int l = r / 5;
  int o = r - l * 5;
  return w * 320 + (o < 4 ? l * 4 + o : 256 + l);
}

__device__ __forceinline__ int wave_iscan(int v, int lane) {
#pragma unroll
  for (int off = 1; off < 64; off <<= 1) {
    int n = __shfl_up(v, off, 64);
    if (lane >= off) v += n;
  }
  return v;
}

// ---- phase 1: per-chunk LDS counting sort by bucket, linear stream-out -----

__global__ __launch_bounds__(512) void k_lsort(const int* __restrict__ src,
                                               const int* __restrict__ dst,
                                               unsigned* __restrict__ colraw,
                                               int* __restrict__ starts2) {
  __shared__ unsigned stage[PA_EPB];   // 62.5 KB
  __shared__ int hist[NBUK];
  __shared__ int tsum[512];
  int b = blockIdx.x, t = threadIdx.x;
  for (int h = t; h < NBUK; h += 512) hist[h] = 0;
  __syncthreads();
  const int4* d4p = (const int4*)dst + (size_t)b * PA_QPB;
  const int4* s4p = (const int4*)src + (size_t)b * PA_QPB;
  for (int i = t; i < PA_QPB; i += 512) {
    int4 d = d4p[i];
    atomicAdd(&hist[d.x >> BSH], 1);
    atomicAdd(&hist[d.y >> BSH], 1);
    atomicAdd(&hist[d.z >> BSH], 1);
    atomicAdd(&hist[d.w >> BSH], 1);
  }
  __syncthreads();
  int h0 = 2 * t, h1 = 2 * t + 1;
  int a0 = (h0 < NBUK) ? hist[h0] : 0;
  int a1 = (h1 < NBUK) ? hist[h1] : 0;
  tsum[t] = a0 + a1;
  __syncthreads();
  for (int o = 1; o < 512; o <<= 1) {
    int v = (t >= o) ? tsum[t - o] : 0;
    __syncthreads();
    tsum[t] += v;
    __syncthreads();
  }
  int ex = tsum[t] - (a0 + a1);
  __syncthreads();
  if (h0 < NBUK) hist[h0] = ex;
  if (h1 < NBUK) hist[h1] = ex + a0;
  __syncthreads();
  int* st = starts2 + (size_t)b * PA_SC;
  for (int h = t; h < NBUK; h += 512) st[h] = hist[h];
  if (t == 0) st[NBUK] = PA_EPB;
  __syncthreads();
  for (int i = t; i < PA_QPB; i += 512) {
    int4 d = d4p[i];
    int4 s = s4p[i];
    int p0 = atomicAdd(&hist[d.x >> BSH], 1);
    stage[p0] = ((unsigned)(d.x & (BNOD - 1)) << 19) | (unsigned)s.x;
    int p1 = atomicAdd(&hist[d.y >> BSH], 1);
    stage[p1] = ((unsigned)(d.y & (BNOD - 1)) << 19) | (unsigned)s.y;
    int p2 = atomicAdd(&hist[d.z >> BSH], 1);
    stage[p2] = ((unsigned)(d.z & (BNOD - 1)) << 19) | (unsigned)s.z;
    int p3 = atomicAdd(&hist[d.w >> BSH], 1);
    stage[p3] = ((unsigned)(d.w & (BNOD - 1)) << 19) | (unsigned)s.w;
  }
  __syncthreads();
  u32x4* out4 = (u32x4*)(colraw + (size_t)b * PA_EPB);
  for (int i = t; i < PA_QPB; i += 512) {
    u32x4 q;
    q[0] = stage[4 * i + 0];
    q[1] = stage[4 * i + 1];
    q[2] = stage[4 * i + 2];
    q[3] = stage[4 * i + 3];
    __builtin_nontemporal_store(q, out4 + i);
  }
}

// ---- phase 2: cooperative run copy + (quarter,dst) sort + swizzle ----------
// Also emits dis[i] and the folded layer-0 gather table qtab.

__global__ __launch_bounds__(512) void k_sortA(const unsigned* __restrict__ colraw,
                                               const int* __restrict__ starts2,
                                               unsigned* __restrict__ col2,
                                               const float2* __restrict__ X,
                                               const float* __restrict__ W0,
                                               const float* __restrict__ step_emb,
                                               const int* __restrict__ step_index,
                                               float* __restrict__ dis,
                                               float2* __restrict__ qtab) {
  __shared__ unsigned stage[SLOT];     // 40 KB
  __shared__ int hist[KEYS];           // 8 KB
  __shared__ int rp[PA_NBLK + 1];      // run start positions (2 KB)
  __shared__ int rs[PA_NBLK];          // run source offsets (2 KB)
  __shared__ int wpart[8];
  __shared__ int qsh[5];
  int h = blockIdx.x, t = threadIdx.x;
  int wv = t >> 6, lane = t & 63;
  // run table from starts2 (one run per chunk)
  int s = 0, len = 0;
  if (t < PA_NBLK) {
    s = starts2[(size_t)t * PA_SC + h];
    len = starts2[(size_t)t * PA_SC + h + 1] - s;
  }
  // zero hist bins (owned 4/thread) before first barrier
  hist[4 * t] = 0;
  hist[4 * t + 1] = 0;
  hist[4 * t + 2] = 0;
  hist[4 * t + 3] = 0;
  // wave scan of run lengths
  int incl = wave_iscan(len, lane);
  if (lane == 63) wpart[wv] = incl;
  __syncthreads();
  int wpre = 0, tot = 0;
#pragma unroll
  for (int k = 0; k < 8; ++k) {
    int pv = wpart[k];
    if (k < wv) wpre += pv;
    tot += pv;
  }
  int pos = wpre + incl - len;  // exclusive prefix
  if (t < PA_NBLK) {
    rp[t] = pos;
    rs[t] = s;
  }
  if (t == 511) rp[PA_NBLK] = tot;
  __syncthreads();
  int ns = tot;
  if (ns > SLOT) ns = SLOT;  // statistically never
  // cooperative run copy: one 16-lane group per run (line-local reads)
  {
    int g = t >> 4, gl = t & 15;  // 32 groups
    for (int r = g; r < PA_NBLK; r += 32) {
      int P = rp[r];
      int L = rp[r + 1] - P;
      const unsigned* rw = colraw + (size_t)r * PA_EPB + rs[r];
      for (int j = gl; j < L; j += 16) {
        int p = P + j;
        if (p < SLOT) stage[p] = rw[j];
      }
    }
  }
  __syncthreads();
  // histogram over (quarter, local_dst)
  for (int i = t; i < ns; i += 512)
    atomicAdd(&hist[(int)(((stage[i] >> 17) & 3u) * BNOD) + (int)(stage[i] >> 19)], 1);
  __syncthreads();
  int deg = hist[t] + hist[t + 512] + hist[t + 1024] + hist[t + 1536];
  int a0 = hist[4 * t], a1 = hist[4 * t + 1], a2 = hist[4 * t + 2], a3 = hist[4 * t + 3];
  int ssum = a0 + a1 + a2 + a3;
  int incl2 = wave_iscan(ssum, lane);
  if (lane == 63) wpart[wv] = incl2;
  __syncthreads();
  int wpre2 = 0;
#pragma unroll
  for (int k = 0; k < 8; ++k) {
    if (k < wv) wpre2 += wpart[k];
  }
  int ex = wpre2 + incl2 - ssum;
  hist[4 * t] = ex;
  hist[4 * t + 1] = ex + a0;
  hist[4 * t + 2] = ex + a0 + a1;
  hist[4 * t + 3] = ex + a0 + a1 + a2;
  if ((t & 127) == 0) qsh[t >> 7] = ex;
  if (t == 511) qsh[4] = ns;
  __syncthreads();
  unsigned* base = col2 + (size_t)h * SLOT;
  for (int i = t; i < ns; i += 512) {
    unsigned p = stage[i];
    int k = (int)(((p >> 17) & 3u) * BNOD) + (int)(p >> 19);
    int posQ = atomicAdd(&hist[k], 1) - qsh[k >> 9];
    if (posQ < SUBQ) base[(k >> 9) * SUBQ + swizQ(posQ)] = p;
  }
  for (int q = 0; q < NQ; ++q) {
    int cnt = qsh[q + 1] - qsh[q];
    if (cnt > SUBQ) cnt = SUBQ;
    if (cnt < 0) cnt = 0;
    for (int j = cnt + t; j < SUBQ; j += 512) base[q * SUBQ + swizQ(j)] = SENT;
  }
  // node init: dis + folded layer-0 gather table
  int i = (h << BSH) + t;
  if (i < NN) {
    float d = rsqrtf((float)deg + 1.0f);
    dis[i] = d;
    float2 x = X[i];
    const float* sv = step_emb + step_index[0] * STEP_DIM;
    float c1_0 = 0.f, c1_1 = 0.f;
#pragma unroll
    for (int j = 0; j < STEP_DIM; ++j) {
      c1_0 += sv[j] * W0[20 + (2 + j) * 2 + 0];
      c1_1 += sv[j] * W0[20 + (2 + j) * 2 + 1];
    }
    qtab[i] = make_float2(d * (x.x * W0[20] + x.y * W0[22] + c1_0),
                          d * (x.x * W0[21] + x.y * W0[23] + c1_1));
  }
}

// ---- layers: batched col2 preload + depth-5 gather prefetch ----------------

__global__ __launch_bounds__(512, 8) void k_blayer0(const unsigned int* __restrict__ col2,
                                                    const float2* __restrict__ qtab,
                                                    const float2* __restrict__ X,
                                                    const float* __restrict__ dis,
                                                    const float* __restrict__ W0,
                                                    const float* __restrict__ b0,
                                                    const float* __restrict__ step_emb,
                                                    const int* __restrict__ step_index,
                                                    float2* __restrict__ xs_out) {
  __shared__ float acc[(BNOD + 1) * 2];
  int b = blockIdx.x, t = threadIdx.x;
  for (int j = t; j < (BNOD + 1) * 2; j += 512) acc[j] = 0.f;
  __syncthreads();
  int w = t >> 6, l = t & 63;
  const unsigned* bp = col2 + (size_t)b * SLOT + w * 320;
  unsigned ebuf[NQ * 5];
#pragma unroll
  for (int q = 0; q < NQ; ++q) {
    u32x4 v = __builtin_nontemporal_load((const u32x4*)(bp + q * SUBQ + l * 4));
    ebuf[q * 5 + 0] = v[0];
    ebuf[q * 5 + 1] = v[1];
    ebuf[q * 5 + 2] = v[2];
    ebuf[q * 5 + 3] = v[3];
    ebuf[q * 5 + 4] = __builtin_nontemporal_load(bp + q * SUBQ + 256 + l);
  }
  int cur = BNOD;
  float rx = 0.f, ry = 0.f;
#pragma unroll
  for (int q = 0; q < NQ; ++q) {
    float2 vals[5];
#pragma unroll
    for (int j = 0; j < 5; ++j) vals[j] = qtab[ebuf[q * 5 + j] & 0x7FFFF];
#pragma unroll
    for (int j = 0; j < 5; ++j) {
      unsigned p = ebuf[q * 5 + j];
      int ld = (int)(p >> 19);
      if (ld != cur) {
        atomicAdd(&acc[cur * 2 + 0], rx);
        atomicAdd(&acc[cur * 2 + 1], ry);
        cur = ld;
        rx = vals[j].x; ry = vals[j].y;
      } else {
        rx += vals[j].x; ry += vals[j].y;
      }
    }
  }
  atomicAdd(&acc[cur * 2 + 0], rx);
  atomicAdd(&acc[cur * 2 + 1], ry);
  __syncthreads();
  const float* sv = step_emb + step_index[0] * STEP_DIM;
  float c00 = b0[0] + b0[2], c01 = b0[1] + b0[3];
#pragma unroll
  for (int j = 0; j < STEP_DIM; ++j) {
    c00 += sv[j] * W0[(2 + j) * 2 + 0];
    c01 += sv[j] * W0[(2 + j) * 2 + 1];
  }
  int i = (b << BSH) + t;
  if (i < NN) {
    float d = dis[i];
    float2 x = X[i];
    float2 qv = qtab[i];
    float h0 = c00 + x.x * W0[0] + x.y * W0[2] + d * (acc[t * 2 + 0] + qv.x);
    float h1 = c01 + x.x * W0[1] + x.y * W0[3] + d * (acc[t * 2 + 1] + qv.y);
    h0 = fmaxf(h0, 0.f);
    h1 = fmaxf(h1, 0.f);
    xs_out[i] = make_float2(d * h0, d * h1);
  }
}

__global__ __launch_bounds__(512, 8) void k_blayer(const unsigned int* __restrict__ col2,
                                                   const float* __restrict__ dis,
                                                   const float2* __restrict__ xs_in,
                                                   const float* __restrict__ W,
                                                   const float* __restrict__ bb,
                                                   float2* __restrict__ xs_out,
                                                   float2* __restrict__ out,
                                                   int last) {
  __shared__ float acc[(BNOD + 1) * 2];
  int b = blockIdx.x, t = threadIdx.x;
  for (int j = t; j < (BNOD + 1) * 2; j += 512) acc[j] = 0.f;
  __syncthreads();
  int w = t >> 6, l = t & 63;
  const unsigned* bp = col2 + (size_t)b * SLOT + w * 320;
  unsigned ebuf[NQ * 5];
#pragma unroll
  for (int q = 0; q < NQ; ++q) {
    u32x4 v = __builtin_nontemporal_load((const u32x4*)(bp + q * SUBQ + l * 4));
    ebuf[q * 5 + 0] = v[0];
    ebuf[q * 5 + 1] = v[1];
    ebuf[q * 5 + 2] = v[2];
    ebuf[q * 5 + 3] = v[3];
    ebuf[q * 5 + 4] = __builtin_nontemporal_load(bp + q * SUBQ + 256 + l);
  }
  int cur = BNOD;
  float rx = 0.f, ry = 0.f;
#pragma unroll
  for (int q = 0; q < NQ; ++q) {
    float2 vals[5];
#pragma unroll
    for (int j = 0; j < 5; ++j) vals[j] = xs_in[ebuf[q * 5 + j] & 0x7FFFF];
#pragma unroll
    for (int j = 0; j < 5; ++j) {
      unsigned p = ebuf[q * 5 + j];
      int ld = (int)(p >> 19);
      if (ld != cur) {
        atomicAdd(&acc[cur * 2 + 0], rx);
        atomicAdd(&acc[cur * 2 + 1], ry);
        cur = ld;
        rx = vals[j].x; ry = vals[j].y;
      } else {
        rx += vals[j].x; ry += vals[j].y;
      }
    }
  }
  atomicAdd(&acc[cur * 2 + 0], rx);
  atomicAdd(&acc[cur * 2 + 1], ry);
  __syncthreads();
  int i = (b << BSH) + t;
  if (i < NN) {
    float d = dis[i];
    float2 xsv = xs_in[i];
    float inv = 1.0f / d;
    float xx = xsv.x * inv, xy = xsv.y * inv;
    float px = d * (acc[t * 2 + 0] + xsv.x);
    float py = d * (acc[t * 2 + 1] + xsv.y);
    float h0 = bb[0] + bb[2] + xx * W[0] + xy * W[2] + px * W[4] + py * W[6];
    float h1 = bb[1] + bb[3] + xx * W[1] + xy * W[3] + px * W[5] + py * W[7];
    h0 = fmaxf(h0, 0.f);
    h1 = fmaxf(h1, 0.f);
    if (last) {
      out[i] = make_float2(h0, h1);
    } else {
      xs_out[i] = make_float2(d * h0, d * h1);
    }
  }
}

// ---- driver ----------------------------------------------------------------

extern "C" void kernel_launch(void* const* d_in, const int* in_sizes, int n_in,
                              void* d_out, int out_size, void* d_ws, size_t ws_size,
                              hipStream_t stream) {
  const float2* X        = (const float2*)d_in[0];
  const int*    edge     = (const int*)d_in[1];
  const int*    src      = edge;
  const int*    dstp     = edge + NE;
  const int*    step_idx = (const int*)d_in[2];
  const float*  step_emb = (const float*)d_in[3];
  const float*  W0       = (const float*)d_in[4];
  const float*  b0       = (const float*)d_in[5];
  const float*  Wh       = (const float*)d_in[6];
  const float*  bbias    = (const float*)d_in[7];

  // ws ints: [col2: 977*10240][colraw: NE][starts2: 500*978 pad]
  //          [dis: 500224][bufA: 1000448][bufB: 1000448]  = 20,994,608 ints (~84 MB)
  int*      ip      = (int*)d_ws;
  unsigned* col2    = (unsigned*)ip;
  size_t    o       = (size_t)NBUK * SLOT;
  unsigned* colraw  = (unsigned*)(ip + o);  o += NE;
  int*      starts2 = ip + o;               o += ((size_t)PA_NBLK * PA_SC + 8) & ~(size_t)3;
  float*    dis     = (float*)(ip + o);     o += 500224;
  float2*   bufA    = (float2*)(ip + o);    o += 2 * 500224;
  float2*   bufB    = (float2*)(ip + o);

  k_lsort<<<PA_NBLK, 512, 0, stream>>>(src, dstp, colraw, starts2);
  k_sortA<<<NBUK, 512, 0, stream>>>(colraw, starts2, col2, X, W0,
                                    step_emb, step_idx, dis, bufA);

  k_blayer0<<<NBUK, 512, 0, stream>>>(col2, bufA, X, dis, W0, b0,
                                      step_emb, step_idx, bufB);
  float2* cur = bufB;
  float2* nxt = bufA;
  for (int l = 0; l < HIDM1; ++l) {
    k_blayer<<<NBUK, 512, 0, stream>>>(col2, dis, cur, Wh + l * 8,
                                       bbias + l * 4, nxt, (float2*)d_out,
                                       l == HIDM1 - 1 ? 1 : 0);
    float2* tmp = cur;
    cur = nxt;
    nxt = tmp;
  }
}